// Round 6
// baseline (217.380 us; speedup 1.0000x reference)
//
#include <hip/hip_runtime.h>
#include <math.h>

#define D_MODEL 512
#define N_SEQ   2048
#define H       8
#define DK      64
#define NQT     (N_SEQ / 128)   // q-tiles per (b,h) = 16

typedef __attribute__((ext_vector_type(8)))  short bf16x8;
typedef __attribute__((ext_vector_type(4)))  float f32x4;
typedef __attribute__((ext_vector_type(16))) float f32x16;

__device__ __forceinline__ unsigned short f2b(float f) {
    unsigned int u = __float_as_uint(f);
    u += 0x7FFF + ((u >> 16) & 1);          // round-to-nearest-even
    return (unsigned short)(u >> 16);
}

__device__ __forceinline__ unsigned int pack2(float lo, float hi) {
#if __has_builtin(__builtin_amdgcn_cvt_pk_bf16_f32)
    typedef __attribute__((ext_vector_type(2))) short bf16x2;
    bf16x2 p = __builtin_amdgcn_cvt_pk_bf16_f32(lo, hi);
    return (unsigned int)(unsigned short)p[0] |
           ((unsigned int)(unsigned short)p[1] << 16);
#else
    return (unsigned int)f2b(lo) | ((unsigned int)f2b(hi) << 16);
#endif
}

__device__ __forceinline__ float fexp2(float x) {
#if __has_builtin(__builtin_amdgcn_exp2f)
    return __builtin_amdgcn_exp2f(x);
#else
    return __expf(x * 0.6931471805599453f);
#endif
}

#define SC2 0.18033688011112042f    // (1/sqrt(64)) * log2(e), folded into Q

// ---------------------------------------------------------------------------
// All four W[512,512] fp32 -> Wt[n][k] bf16, one launch (z picks the matrix)
// ---------------------------------------------------------------------------
__global__ void transpose_all(
    const float* __restrict__ W0, const float* __restrict__ W1,
    const float* __restrict__ W2, const float* __restrict__ W3,
    unsigned short* __restrict__ T0, unsigned short* __restrict__ T1,
    unsigned short* __restrict__ T2, unsigned short* __restrict__ T3)
{
    const float* W; unsigned short* Wt;
    if      (blockIdx.z == 0) { W = W0; Wt = T0; }
    else if (blockIdx.z == 1) { W = W1; Wt = T1; }
    else if (blockIdx.z == 2) { W = W2; Wt = T2; }
    else                      { W = W3; Wt = T3; }

    __shared__ float t[32][33];
    const int tx = threadIdx.x, ty = threadIdx.y;
    const int x = blockIdx.x * 32 + tx;
    const int y0 = blockIdx.y * 32;
    for (int i = ty; i < 32; i += 8)
        t[i][tx] = W[(size_t)(y0 + i) * D_MODEL + x];
    __syncthreads();
    const int ox = blockIdx.y * 32 + tx;
    const int oy0 = blockIdx.x * 32;
    for (int i = ty; i < 32; i += 8)
        Wt[(size_t)(oy0 + i) * D_MODEL + ox] = f2b(t[tx][i]);
}

// ---------------------------------------------------------------------------
// bf16 MFMA GEMM body (16x16x32).
// AMODE 1: A fp32, converted during staging.  AMODE 0: A bf16.
// SWAP 1 (Q/K): MFMA called as (Wfrag, xfrag) so C cols = tokens, rows = d
//               -> packed ushort4 d-contiguous stores to [B,H,N,DK].
// SWAP 0: mode 1 V^T [B,H,DK,N] (token-packed), mode 2 fp32 [M,512].
// Epilogue applies (acc + bias) * sc  (sc = SC2 for the Q matrix).
// ---------------------------------------------------------------------------
template<int AMODE, int SWAP>
__device__ __forceinline__ void gemm_body(
    const void* __restrict__ Aptr,
    const unsigned short* __restrict__ Wt,
    const float* __restrict__ bias,
    void* __restrict__ out, int mode, int bx, int by, float sc)
{
    __shared__ unsigned short As[128][72];
    __shared__ unsigned short Bs[128][72];

    const int tid  = threadIdx.x;
    const int lane = tid & 63, wave = tid >> 6;
    const int m0 = by * 128, n0 = bx * 128;
    const int wm = (wave & 1) * 64, wn = (wave >> 1) * 64;
    const int cn = lane & 15, g = lane >> 4;

    const int srow = tid >> 1;
    const int scol = (tid & 1) * 32;
    const float* Agf = (const float*)Aptr + (size_t)(m0 + srow) * D_MODEL + scol;
    const unsigned short* Agb =
        (const unsigned short*)Aptr + (size_t)(m0 + srow) * D_MODEL + scol;
    const unsigned short* Bg = Wt + (size_t)(n0 + srow) * D_MODEL + scol;

    f32x4 acc[4][4];
    #pragma unroll
    for (int i = 0; i < 4; ++i)
        #pragma unroll
        for (int j = 0; j < 4; ++j)
            acc[i][j] = (f32x4){0.f, 0.f, 0.f, 0.f};

    for (int k0 = 0; k0 < D_MODEL; k0 += 64) {
        bf16x8 av[4], bv[4];
        #pragma unroll
        for (int q = 0; q < 4; ++q) {
            if (AMODE) {
                float4 f0 = *(const float4*)(Agf + k0 + q * 8);
                float4 f1 = *(const float4*)(Agf + k0 + q * 8 + 4);
                unsigned int* pv = (unsigned int*)&av[q];
                pv[0] = pack2(f0.x, f0.y); pv[1] = pack2(f0.z, f0.w);
                pv[2] = pack2(f1.x, f1.y); pv[3] = pack2(f1.z, f1.w);
            } else {
                av[q] = *(const bf16x8*)(Agb + k0 + q * 8);
            }
            bv[q] = *(const bf16x8*)(Bg + k0 + q * 8);
        }
        __syncthreads();
        #pragma unroll
        for (int q = 0; q < 4; ++q) {
            *(bf16x8*)&As[srow][scol + q * 8] = av[q];
            *(bf16x8*)&Bs[srow][scol + q * 8] = bv[q];
        }
        __syncthreads();

        #pragma unroll
        for (int ks = 0; ks < 2; ++ks) {
            bf16x8 af[4], bf[4];
            #pragma unroll
            for (int i = 0; i < 4; ++i)
                af[i] = *(const bf16x8*)&As[wm + i * 16 + cn][ks * 32 + g * 8];
            #pragma unroll
            for (int j = 0; j < 4; ++j)
                bf[j] = *(const bf16x8*)&Bs[wn + j * 16 + cn][ks * 32 + g * 8];
            #pragma unroll
            for (int i = 0; i < 4; ++i)
                #pragma unroll
                for (int j = 0; j < 4; ++j) {
                    if (SWAP)
                        acc[i][j] = __builtin_amdgcn_mfma_f32_16x16x32_bf16(
                            bf[j], af[i], acc[i][j], 0, 0, 0);
                    else
                        acc[i][j] = __builtin_amdgcn_mfma_f32_16x16x32_bf16(
                            af[i], bf[j], acc[i][j], 0, 0, 0);
                }
        }
    }

    if constexpr (SWAP) {
        // C tile: rows = W-dim (d), cols = tokens.  reg r -> d offset g*4+r,
        // lane cn -> token.  Pack 4 d-contiguous values per store.
        unsigned short* o = (unsigned short*)out;
        #pragma unroll
        for (int j = 0; j < 4; ++j) {
            const int dbase = n0 + wn + j * 16 + g * 4;
            const int hh = dbase >> 6, dd = dbase & 63;
            float4 bb = *(const float4*)&bias[dbase];
            #pragma unroll
            for (int i = 0; i < 4; ++i) {
                const int tt = m0 + wm + i * 16 + cn;
                const int bi = tt >> 11, tok = tt & (N_SEQ - 1);
                ushort4 pk;
                pk.x = f2b((acc[i][j][0] + bb.x) * sc);
                pk.y = f2b((acc[i][j][1] + bb.y) * sc);
                pk.z = f2b((acc[i][j][2] + bb.z) * sc);
                pk.w = f2b((acc[i][j][3] + bb.w) * sc);
                *(ushort4*)(o + (((size_t)bi * H + hh) * N_SEQ + tok) * DK + dd) = pk;
            }
        }
    } else if (mode == 2) {
        float* o = (float*)out;
        #pragma unroll
        for (int j = 0; j < 4; ++j) {
            const int n = n0 + wn + j * 16 + cn;
            const float bb = bias[n];
            #pragma unroll
            for (int i = 0; i < 4; ++i)
                #pragma unroll
                for (int r = 0; r < 4; ++r) {
                    const int m = m0 + wm + i * 16 + g * 4 + r;
                    o[(size_t)m * D_MODEL + n] = acc[i][j][r] + bb;
                }
        }
    } else {                                 // V^T: [B,H,DK,N] bf16
        unsigned short* o = (unsigned short*)out;
        #pragma unroll
        for (int j = 0; j < 4; ++j) {
            const int n = n0 + wn + j * 16 + cn;
            const int h = n >> 6, d = n & 63;
            const float bb = bias[n];
            #pragma unroll
            for (int i = 0; i < 4; ++i) {
                const int m = m0 + wm + i * 16 + g * 4;
                const int b = m >> 11, t = m & (N_SEQ - 1);
                ushort4 pk;
                pk.x = f2b(acc[i][j][0] + bb);
                pk.y = f2b(acc[i][j][1] + bb);
                pk.z = f2b(acc[i][j][2] + bb);
                pk.w = f2b(acc[i][j][3] + bb);
                *(ushort4*)(o + (((size_t)b * H + h) * DK + d) * N_SEQ + t) = pk;
            }
        }
    }
}

__global__ __launch_bounds__(256) void gemm_qkv(
    const float* __restrict__ x,
    const unsigned short* __restrict__ Wtq,
    const unsigned short* __restrict__ Wtk,
    const unsigned short* __restrict__ Wtv,
    const float* __restrict__ bq, const float* __restrict__ bk,
    const float* __restrict__ bv,
    unsigned short* __restrict__ Qb, unsigned short* __restrict__ Kb,
    unsigned short* __restrict__ Vtb)
{
    if (blockIdx.z == 0)
        gemm_body<1, 1>(x, Wtq, bq, Qb, 0, blockIdx.x, blockIdx.y, SC2);
    else if (blockIdx.z == 1)
        gemm_body<1, 1>(x, Wtk, bk, Kb, 0, blockIdx.x, blockIdx.y, 1.0f);
    else
        gemm_body<1, 0>(x, Wtv, bv, Vtb, 1, blockIdx.x, blockIdx.y, 1.0f);
}

__global__ __launch_bounds__(256) void gemm_o(
    const unsigned short* __restrict__ A,
    const unsigned short* __restrict__ Wt,
    const float* __restrict__ bias, float* __restrict__ out)
{
    gemm_body<0, 0>(A, Wt, bias, out, 2, blockIdx.x, blockIdx.y, 1.0f);
}

// ---------------------------------------------------------------------------
// Flash attention, 32x32x16 MFMA, split-kv x2, static softmax (Q pre-scaled
// by SC2 so p = exp2(s)).  P never touches LDS: the C->B-operand transform is
// a lane<->lane^32 exchange of packed bf16 pairs.  l accumulated in-lane from
// the SAME rounded values.  Unnormalized O^T + l written as fp32 partials.
// ---------------------------------------------------------------------------
__global__ __launch_bounds__(256, 4) void attn_mfma(
    const unsigned short* __restrict__ Q,
    const unsigned short* __restrict__ K,
    const unsigned short* __restrict__ Vt,
    float* __restrict__ Op, float* __restrict__ lp, int nb)
{
    __shared__ unsigned short Ks[64][72];       // [kv][d]
    __shared__ unsigned short Vs[64][72];       // [d][kv]

    const int tid = threadIdx.x, lane = tid & 63, wave = tid >> 6;
    const int qt = blockIdx.x, h = blockIdx.y;
    const int b = blockIdx.z >> 1, sp = blockIdx.z & 1;
    const int lq = lane & 31, hf = lane >> 5;
    const int q0 = qt * 128;

    const size_t hb = (size_t)b * H + h;
    const unsigned short* Qp = Q  + hb * N_SEQ * DK;
    const unsigned short* Kp = K  + hb * N_SEQ * DK;
    const unsigned short* Vp = Vt + hb * DK * N_SEQ;

    const int qs = q0 + wave * 32;
    bf16x8 qf[4];
    #pragma unroll
    for (int kd = 0; kd < 4; ++kd)
        qf[kd] = *(const bf16x8*)(Qp + (size_t)(qs + lq) * DK + kd * 16 + hf * 8);

    f32x16 O[2];
    #pragma unroll
    for (int r = 0; r < 16; ++r) { O[0][r] = 0.f; O[1][r] = 0.f; }
    float lacc = 0.f;

    const int krow = tid >> 2, kcol = (tid & 3) * 16;
    const int j0beg = sp * (N_SEQ / 2);

    for (int j0 = j0beg; j0 < j0beg + N_SEQ / 2; j0 += 64) {
        bf16x8 kv0 = *(const bf16x8*)(Kp + (size_t)(j0 + krow) * DK + kcol);
        bf16x8 kv1 = *(const bf16x8*)(Kp + (size_t)(j0 + krow) * DK + kcol + 8);
        bf16x8 vv0 = *(const bf16x8*)(Vp + (size_t)krow * N_SEQ + j0 + kcol);
        bf16x8 vv1 = *(const bf16x8*)(Vp + (size_t)krow * N_SEQ + j0 + kcol + 8);
        __syncthreads();
        *(bf16x8*)&Ks[krow][kcol]     = kv0;
        *(bf16x8*)&Ks[krow][kcol + 8] = kv1;
        *(bf16x8*)&Vs[krow][kcol]     = vv0;
        *(bf16x8*)&Vs[krow][kcol + 8] = vv1;
        __syncthreads();

        // S^T[kv][q] already in log2 domain (Q pre-scaled by SC2)
        f32x16 s0, s1;
        #pragma unroll
        for (int r = 0; r < 16; ++r) { s0[r] = 0.f; s1[r] = 0.f; }
        #pragma unroll
        for (int kd = 0; kd < 4; ++kd) {
            bf16x8 a0 = *(const bf16x8*)&Ks[lq][kd * 16 + hf * 8];
            bf16x8 a1 = *(const bf16x8*)&Ks[32 + lq][kd * 16 + hf * 8];
            s0 = __builtin_amdgcn_mfma_f32_32x32x16_bf16(a0, qf[kd], s0, 0, 0, 0);
            s1 = __builtin_amdgcn_mfma_f32_32x32x16_bf16(a1, qf[kd], s1, 0, 0, 0);
        }

        // p = exp2(s) packed as bf16 pairs; pk[c][p] = regs (4c+2p, 4c+2p+1)
        unsigned int pk0[4][2], pk1[4][2];
        #pragma unroll
        for (int c = 0; c < 4; ++c)
            #pragma unroll
            for (int p = 0; p < 2; ++p) {
                pk0[c][p] = pack2(fexp2(s0[4 * c + 2 * p]),
                                  fexp2(s0[4 * c + 2 * p + 1]));
                pk1[c][p] = pack2(fexp2(s1[4 * c + 2 * p]),
                                  fexp2(s1[4 * c + 2 * p + 1]));
            }

        // l += sum of own (rounded) p values — all belong to column q=lq
        #pragma unroll
        for (int c = 0; c < 4; ++c)
            #pragma unroll
            for (int p = 0; p < 2; ++p) {
                lacc += __uint_as_float(pk0[c][p] << 16) +
                        __uint_as_float(pk0[c][p] & 0xFFFF0000u) +
                        __uint_as_float(pk1[c][p] << 16) +
                        __uint_as_float(pk1[c][p] & 0xFFFF0000u);
            }

        // O^T += V^T . P^T : B-frag built by lane^32 exchange.
        // dest (lq,hf), kv block ks: j0..3 from hf_src=0 lane, j4..7 from
        // hf_src=1 lane, both at c = 2*(ks&1)+hf of the right tile.
        #pragma unroll
        for (int ks = 0; ks < 4; ++ks) {
            const unsigned int (*src)[2] = (ks < 2) ? pk0 : pk1;
            const int k2 = ks & 1;
            const unsigned int a0u = src[2 * k2 + hf][0];
            const unsigned int a1u = src[2 * k2 + hf][1];
            const unsigned int b0u = src[2 * k2 + 1 - hf][0];
            const unsigned int b1u = src[2 * k2 + 1 - hf][1];
            const unsigned int e0 = (unsigned int)__shfl_xor((int)b0u, 32);
            const unsigned int e1 = (unsigned int)__shfl_xor((int)b1u, 32);
            bf16x8 bp;
            unsigned int* bpu = (unsigned int*)&bp;
            bpu[0] = hf ? e0 : a0u;
            bpu[1] = hf ? e1 : a1u;
            bpu[2] = hf ? a0u : e0;
            bpu[3] = hf ? a1u : e1;
            bf16x8 va0 = *(const bf16x8*)&Vs[lq][ks * 16 + hf * 8];
            bf16x8 va1 = *(const bf16x8*)&Vs[32 + lq][ks * 16 + hf * 8];
            O[0] = __builtin_amdgcn_mfma_f32_32x32x16_bf16(va0, bp, O[0], 0, 0, 0);
            O[1] = __builtin_amdgcn_mfma_f32_32x32x16_bf16(va1, bp, O[1], 0, 0, 0);
        }
    }

    // write fp32 partials: O^T tile [64 d][128 q] + l strip
    const size_t pbase =
        ((((size_t)sp * nb + b) * H + h) * NQT + qt) * (size_t)(64 * 128);
    #pragma unroll
    for (int dt = 0; dt < 2; ++dt)
        #pragma unroll
        for (int r = 0; r < 16; ++r) {
            const int row = (r & 3) + 8 * (r >> 2) + 4 * hf;
            Op[pbase + (size_t)(dt * 32 + row) * 128 + wave * 32 + lq] = O[dt][r];
        }
    const float lt = lacc + __shfl_xor(lacc, 32);
    if (hf == 0)
        lp[(((size_t)sp * nb + b) * H + h) * N_SEQ + q0 + wave * 32 + lq] = lt;
}

// ---------------------------------------------------------------------------
// Sum 2 partials, divide by l, transpose [d][q] -> [q][d], write ctx bf16.
// ---------------------------------------------------------------------------
__global__ __launch_bounds__(256) void reduce_ctx(
    const float* __restrict__ Op, const float* __restrict__ lp,
    unsigned short* __restrict__ ctx, int nb)
{
    __shared__ float R[64][129];
    const int tid = threadIdx.x;
    const int qt = blockIdx.x, h = blockIdx.y, b = blockIdx.z;
    const size_t tile = (size_t)64 * 128;
    const size_t i0 = (((size_t)b * H + h) * NQT + qt) * tile;
    const size_t i1 = ((((size_t)nb + b) * H + h) * NQT + qt) * tile;

    #pragma unroll 4
    for (int u = 0; u < 32; ++u) {
        const int idx = u * 256 + tid;
        R[idx >> 7][idx & 127] = Op[i0 + idx] + Op[i1 + idx];
    }
    __syncthreads();

    const int q = tid & 127, dh = tid >> 7;
    const size_t lb = ((size_t)b * H + h) * N_SEQ + qt * 128 + q;
    const float inv = 1.0f / (lp[lb] + lp[(size_t)nb * H * N_SEQ + lb]);

    unsigned short* orow = ctx + ((size_t)b * N_SEQ + qt * 128 + q) * D_MODEL
                               + h * DK + dh * 32;
    #pragma unroll
    for (int t2 = 0; t2 < 4; ++t2) {
        unsigned int w[4];
        #pragma unroll
        for (int p = 0; p < 4; ++p)
            w[p] = pack2(R[dh * 32 + t2 * 8 + 2 * p][q] * inv,
                         R[dh * 32 + t2 * 8 + 2 * p + 1][q] * inv);
        *(bf16x8*)(orow + t2 * 8) = *(bf16x8*)w;
    }
}

// ---------------------------------------------------------------------------
extern "C" void kernel_launch(void* const* d_in, const int* in_sizes, int n_in,
                              void* d_out, int out_size, void* d_ws, size_t ws_size,
                              hipStream_t stream)
{
    const float* x  = (const float*)d_in[0];
    const float* Wq = (const float*)d_in[1];
    const float* bq = (const float*)d_in[2];
    const float* Wk = (const float*)d_in[3];
    const float* bk = (const float*)d_in[4];
    const float* Wv = (const float*)d_in[5];
    const float* bv = (const float*)d_in[6];
    const float* Wo = (const float*)d_in[7];
    const float* bo = (const float*)d_in[8];
    float* out = (float*)d_out;

    const int M = in_sizes[0] / D_MODEL;        // 8192
    const int nb = M / N_SEQ;                   // 4
    const size_t NX = (size_t)M * D_MODEL;
    const size_t NW = (size_t)D_MODEL * D_MODEL;

    unsigned short* Wtq = (unsigned short*)d_ws;
    unsigned short* Wtk = Wtq + NW;
    unsigned short* Wtv = Wtk + NW;
    unsigned short* Wto = Wtv + NW;
    unsigned short* Qb  = Wto + NW;
    unsigned short* Kb  = Qb + NX;
    unsigned short* Vtb = Kb + NX;
    float* Op = (float*)(Vtb + NX);             // 2 * nb*H*NQT * 8192 floats
    float* lp = Op + (size_t)2 * nb * H * NQT * 8192;
    unsigned short* ctx = Qb;                   // Qb dead after attn — alias

    transpose_all<<<dim3(16, 16, 4), dim3(32, 8), 0, stream>>>(
        Wq, Wk, Wv, Wo, Wtq, Wtk, Wtv, Wto);

    gemm_qkv<<<dim3(D_MODEL / 128, M / 128, 3), 256, 0, stream>>>(
        x, Wtq, Wtk, Wtv, bq, bk, bv, Qb, Kb, Vtb);
    attn_mfma<<<dim3(NQT, H, nb * 2), 256, 0, stream>>>(Qb, Kb, Vtb, Op, lp, nb);
    reduce_ctx<<<dim3(NQT, H, nb), 256, 0, stream>>>(Op, lp, ctx, nb);
    gemm_o<<<dim3(D_MODEL / 128, M / 128), 256, 0, stream>>>(ctx, Wto, bo, out);
}

// Round 7
// 190.433 us; speedup vs baseline: 1.1415x; 1.1415x over previous
//
#include <hip/hip_runtime.h>
#include <math.h>

#define D_MODEL 512
#define N_SEQ   2048
#define H       8
#define DK      64
#define NQT     (N_SEQ / 128)   // q-tiles per (b,h) = 16

typedef __attribute__((ext_vector_type(8)))  short bf16x8;
typedef __attribute__((ext_vector_type(4)))  float f32x4;
typedef __attribute__((ext_vector_type(16))) float f32x16;

__device__ __forceinline__ unsigned short f2b(float f) {
    unsigned int u = __float_as_uint(f);
    u += 0x7FFF + ((u >> 16) & 1);          // round-to-nearest-even
    return (unsigned short)(u >> 16);
}

__device__ __forceinline__ unsigned int pack2(float lo, float hi) {
#if __has_builtin(__builtin_amdgcn_cvt_pk_bf16_f32)
    typedef __attribute__((ext_vector_type(2))) short bf16x2;
    bf16x2 p = __builtin_amdgcn_cvt_pk_bf16_f32(lo, hi);
    return (unsigned int)(unsigned short)p[0] |
           ((unsigned int)(unsigned short)p[1] << 16);
#else
    return (unsigned int)f2b(lo) | ((unsigned int)f2b(hi) << 16);
#endif
}

__device__ __forceinline__ float fexp2(float x) {
#if __has_builtin(__builtin_amdgcn_exp2f)
    return __builtin_amdgcn_exp2f(x);
#else
    return __expf(x * 0.6931471805599453f);
#endif
}

#define SC2 0.18033688011112042f    // (1/sqrt(64)) * log2(e), folded into Q

// ---------------------------------------------------------------------------
// All four W[512,512] fp32 -> Wt[n][k] bf16, one launch (z picks the matrix)
// ---------------------------------------------------------------------------
__global__ void transpose_all(
    const float* __restrict__ W0, const float* __restrict__ W1,
    const float* __restrict__ W2, const float* __restrict__ W3,
    unsigned short* __restrict__ T0, unsigned short* __restrict__ T1,
    unsigned short* __restrict__ T2, unsigned short* __restrict__ T3)
{
    const float* W; unsigned short* Wt;
    if      (blockIdx.z == 0) { W = W0; Wt = T0; }
    else if (blockIdx.z == 1) { W = W1; Wt = T1; }
    else if (blockIdx.z == 2) { W = W2; Wt = T2; }
    else                      { W = W3; Wt = T3; }

    __shared__ float t[32][33];
    const int tx = threadIdx.x, ty = threadIdx.y;
    const int x = blockIdx.x * 32 + tx;
    const int y0 = blockIdx.y * 32;
    for (int i = ty; i < 32; i += 8)
        t[i][tx] = W[(size_t)(y0 + i) * D_MODEL + x];
    __syncthreads();
    const int ox = blockIdx.y * 32 + tx;
    const int oy0 = blockIdx.x * 32;
    for (int i = ty; i < 32; i += 8)
        Wt[(size_t)(oy0 + i) * D_MODEL + ox] = f2b(t[tx][i]);
}

// ---------------------------------------------------------------------------
// bf16 MFMA GEMM body (16x16x32).
// AMODE 1: A fp32, converted during staging.  AMODE 0: A bf16.
// SWAP 1 (Q/K): MFMA called as (Wfrag, xfrag) so C cols = tokens, rows = d
//               -> packed ushort4 d-contiguous stores to [B,H,N,DK].
// SWAP 0: mode 1 V^T [B,H,DK,N] (token-packed), mode 2 fp32 [M,512].
// Epilogue applies (acc + bias) * sc  (sc = SC2 for the Q matrix).
// ---------------------------------------------------------------------------
template<int AMODE, int SWAP>
__device__ __forceinline__ void gemm_body(
    const void* __restrict__ Aptr,
    const unsigned short* __restrict__ Wt,
    const float* __restrict__ bias,
    void* __restrict__ out, int mode, int bx, int by, float sc)
{
    __shared__ unsigned short As[128][72];
    __shared__ unsigned short Bs[128][72];

    const int tid  = threadIdx.x;
    const int lane = tid & 63, wave = tid >> 6;
    const int m0 = by * 128, n0 = bx * 128;
    const int wm = (wave & 1) * 64, wn = (wave >> 1) * 64;
    const int cn = lane & 15, g = lane >> 4;

    const int srow = tid >> 1;
    const int scol = (tid & 1) * 32;
    const float* Agf = (const float*)Aptr + (size_t)(m0 + srow) * D_MODEL + scol;
    const unsigned short* Agb =
        (const unsigned short*)Aptr + (size_t)(m0 + srow) * D_MODEL + scol;
    const unsigned short* Bg = Wt + (size_t)(n0 + srow) * D_MODEL + scol;

    f32x4 acc[4][4];
    #pragma unroll
    for (int i = 0; i < 4; ++i)
        #pragma unroll
        for (int j = 0; j < 4; ++j)
            acc[i][j] = (f32x4){0.f, 0.f, 0.f, 0.f};

    for (int k0 = 0; k0 < D_MODEL; k0 += 64) {
        bf16x8 av[4], bv[4];
        #pragma unroll
        for (int q = 0; q < 4; ++q) {
            if (AMODE) {
                float4 f0 = *(const float4*)(Agf + k0 + q * 8);
                float4 f1 = *(const float4*)(Agf + k0 + q * 8 + 4);
                unsigned int* pv = (unsigned int*)&av[q];
                pv[0] = pack2(f0.x, f0.y); pv[1] = pack2(f0.z, f0.w);
                pv[2] = pack2(f1.x, f1.y); pv[3] = pack2(f1.z, f1.w);
            } else {
                av[q] = *(const bf16x8*)(Agb + k0 + q * 8);
            }
            bv[q] = *(const bf16x8*)(Bg + k0 + q * 8);
        }
        __syncthreads();
        #pragma unroll
        for (int q = 0; q < 4; ++q) {
            *(bf16x8*)&As[srow][scol + q * 8] = av[q];
            *(bf16x8*)&Bs[srow][scol + q * 8] = bv[q];
        }
        __syncthreads();

        #pragma unroll
        for (int ks = 0; ks < 2; ++ks) {
            bf16x8 af[4], bf[4];
            #pragma unroll
            for (int i = 0; i < 4; ++i)
                af[i] = *(const bf16x8*)&As[wm + i * 16 + cn][ks * 32 + g * 8];
            #pragma unroll
            for (int j = 0; j < 4; ++j)
                bf[j] = *(const bf16x8*)&Bs[wn + j * 16 + cn][ks * 32 + g * 8];
            #pragma unroll
            for (int i = 0; i < 4; ++i)
                #pragma unroll
                for (int j = 0; j < 4; ++j) {
                    if (SWAP)
                        acc[i][j] = __builtin_amdgcn_mfma_f32_16x16x32_bf16(
                            bf[j], af[i], acc[i][j], 0, 0, 0);
                    else
                        acc[i][j] = __builtin_amdgcn_mfma_f32_16x16x32_bf16(
                            af[i], bf[j], acc[i][j], 0, 0, 0);
                }
        }
    }

    if constexpr (SWAP) {
        unsigned short* o = (unsigned short*)out;
        #pragma unroll
        for (int j = 0; j < 4; ++j) {
            const int dbase = n0 + wn + j * 16 + g * 4;
            const int hh = dbase >> 6, dd = dbase & 63;
            float4 bb = *(const float4*)&bias[dbase];
            #pragma unroll
            for (int i = 0; i < 4; ++i) {
                const int tt = m0 + wm + i * 16 + cn;
                const int bi = tt >> 11, tok = tt & (N_SEQ - 1);
                ushort4 pk;
                pk.x = f2b((acc[i][j][0] + bb.x) * sc);
                pk.y = f2b((acc[i][j][1] + bb.y) * sc);
                pk.z = f2b((acc[i][j][2] + bb.z) * sc);
                pk.w = f2b((acc[i][j][3] + bb.w) * sc);
                *(ushort4*)(o + (((size_t)bi * H + hh) * N_SEQ + tok) * DK + dd) = pk;
            }
        }
    } else if (mode == 2) {
        float* o = (float*)out;
        #pragma unroll
        for (int j = 0; j < 4; ++j) {
            const int n = n0 + wn + j * 16 + cn;
            const float bb = bias[n];
            #pragma unroll
            for (int i = 0; i < 4; ++i)
                #pragma unroll
                for (int r = 0; r < 4; ++r) {
                    const int m = m0 + wm + i * 16 + g * 4 + r;
                    o[(size_t)m * D_MODEL + n] = acc[i][j][r] + bb;
                }
        }
    } else {                                 // V^T: [B,H,DK,N] bf16
        unsigned short* o = (unsigned short*)out;
        #pragma unroll
        for (int j = 0; j < 4; ++j) {
            const int n = n0 + wn + j * 16 + cn;
            const int h = n >> 6, d = n & 63;
            const float bb = bias[n];
            #pragma unroll
            for (int i = 0; i < 4; ++i) {
                const int m = m0 + wm + i * 16 + g * 4;
                const int b = m >> 11, t = m & (N_SEQ - 1);
                ushort4 pk;
                pk.x = f2b(acc[i][j][0] + bb);
                pk.y = f2b(acc[i][j][1] + bb);
                pk.z = f2b(acc[i][j][2] + bb);
                pk.w = f2b(acc[i][j][3] + bb);
                *(ushort4*)(o + (((size_t)b * H + h) * DK + d) * N_SEQ + t) = pk;
            }
        }
    }
}

__global__ __launch_bounds__(256) void gemm_qkv(
    const float* __restrict__ x,
    const unsigned short* __restrict__ Wtq,
    const unsigned short* __restrict__ Wtk,
    const unsigned short* __restrict__ Wtv,
    const float* __restrict__ bq, const float* __restrict__ bk,
    const float* __restrict__ bv,
    unsigned short* __restrict__ Qb, unsigned short* __restrict__ Kb,
    unsigned short* __restrict__ Vtb)
{
    if (blockIdx.z == 0)
        gemm_body<1, 1>(x, Wtq, bq, Qb, 0, blockIdx.x, blockIdx.y, SC2);
    else if (blockIdx.z == 1)
        gemm_body<1, 1>(x, Wtk, bk, Kb, 0, blockIdx.x, blockIdx.y, 1.0f);
    else
        gemm_body<1, 0>(x, Wtv, bv, Vtb, 1, blockIdx.x, blockIdx.y, 1.0f);
}

__global__ __launch_bounds__(256) void gemm_o(
    const unsigned short* __restrict__ A,
    const unsigned short* __restrict__ Wt,
    const float* __restrict__ bias, float* __restrict__ out)
{
    gemm_body<0, 0>(A, Wt, bias, out, 2, blockIdx.x, blockIdx.y, 1.0f);
}

// ---------------------------------------------------------------------------
// Flash attention, 32x32x16 MFMA, static softmax (Q pre-scaled by SC2).
//
// Zero-shuffle P path: MFMA is invariant to any permutation of K applied to
// both operands.  We permute each 16-kv chunk as [quad0,quad2,quad1,quad3],
// which makes the PV B-operand EXACTLY the lane's own packed S^T C-register
// quads (lane (q,hf) holds kv quads {4hf+8c}); V^T absorbs the permutation
// by swapping the middle quads of each 16-col chunk at staging (register
// regrouping, free).  l via ones-A MFMA (permutation-invariant sum).
//
// Intra-block split-kv: 512 threads = 8 waves; waves 0-3 do kv[0,1024),
// waves 4-7 do kv[1024,2048) with separate LDS tile pairs; partials combine
// through LDS once at the end.  2 blocks/CU -> 16 waves/CU.
// ---------------------------------------------------------------------------
__global__ __launch_bounds__(512, 4) void attn_mfma(
    const unsigned short* __restrict__ Q,
    const unsigned short* __restrict__ K,
    const unsigned short* __restrict__ Vt,
    unsigned short* __restrict__ ctx)
{
    __shared__ unsigned short SM[2][2][64][72];   // [kv-half][K|V][row][col]

    const int tid = threadIdx.x, lane = tid & 63, wave = tid >> 6;
    const int qt = blockIdx.x, h = blockIdx.y, b = blockIdx.z;
    const int sp = wave >> 2;                 // kv half
    const int w4 = wave & 3;                  // q-strip within tile
    const int lq = lane & 31, hf = lane >> 5;
    const int q0 = qt * 128;
    const int qs = q0 + w4 * 32;

    const size_t hb = (size_t)b * H + h;
    const unsigned short* Qp = Q  + hb * N_SEQ * DK;
    const unsigned short* Kp = K  + hb * N_SEQ * DK;
    const unsigned short* Vp = Vt + hb * DK * N_SEQ;

    bf16x8 qf[4];
    #pragma unroll
    for (int kd = 0; kd < 4; ++kd)
        qf[kd] = *(const bf16x8*)(Qp + (size_t)(qs + lq) * DK + kd * 16 + hf * 8);

    f32x16 O[2], Ol;
    #pragma unroll
    for (int r = 0; r < 16; ++r) { O[0][r] = 0.f; O[1][r] = 0.f; Ol[r] = 0.f; }

    bf16x8 onesA;                             // A ones-frag: row m==0 only
    {
        const short v = (lq == 0) ? (short)0x3F80 : (short)0;
        #pragma unroll
        for (int j = 0; j < 8; ++j) onesA[j] = v;
    }

    const int tl = tid & 255;                 // index within kv-half group
    const int krow = tl >> 2, kcol = (tl & 3) * 16;
    unsigned short (*Ks)[72] = SM[sp][0];
    unsigned short (*Vs)[72] = SM[sp][1];

    for (int it = 0; it < 16; ++it) {
        const int j0 = sp * (N_SEQ / 2) + it * 64;
        bf16x8 kv0 = *(const bf16x8*)(Kp + (size_t)(j0 + krow) * DK + kcol);
        bf16x8 kv1 = *(const bf16x8*)(Kp + (size_t)(j0 + krow) * DK + kcol + 8);
        bf16x8 vv0 = *(const bf16x8*)(Vp + (size_t)krow * N_SEQ + j0 + kcol);
        bf16x8 vv1 = *(const bf16x8*)(Vp + (size_t)krow * N_SEQ + j0 + kcol + 8);
        // sigma: swap middle quads of the 16-col chunk: store (q0,q2),(q1,q3)
        bf16x8 sw0, sw1;
        {
            ushort4* a = (ushort4*)&vv0;
            ushort4* c = (ushort4*)&vv1;
            ushort4* s0p = (ushort4*)&sw0;
            ushort4* s1p = (ushort4*)&sw1;
            s0p[0] = a[0]; s0p[1] = c[0];
            s1p[0] = a[1]; s1p[1] = c[1];
        }
        __syncthreads();
        *(bf16x8*)&Ks[krow][kcol]     = kv0;
        *(bf16x8*)&Ks[krow][kcol + 8] = kv1;
        *(bf16x8*)&Vs[krow][kcol]     = sw0;
        *(bf16x8*)&Vs[krow][kcol + 8] = sw1;
        __syncthreads();

        // S^T[kv][q] (log2 domain): lane holds col q=lq, rows kv per C map
        f32x16 s0, s1;
        #pragma unroll
        for (int r = 0; r < 16; ++r) { s0[r] = 0.f; s1[r] = 0.f; }
        #pragma unroll
        for (int kd = 0; kd < 4; ++kd) {
            bf16x8 a0 = *(const bf16x8*)&Ks[lq][kd * 16 + hf * 8];
            bf16x8 a1 = *(const bf16x8*)&Ks[32 + lq][kd * 16 + hf * 8];
            s0 = __builtin_amdgcn_mfma_f32_32x32x16_bf16(a0, qf[kd], s0, 0, 0, 0);
            s1 = __builtin_amdgcn_mfma_f32_32x32x16_bf16(a1, qf[kd], s1, 0, 0, 0);
        }

        // p = exp2(s); pk[c][p] = packed regs (4c+2p, 4c+2p+1) = kv quads
        unsigned int pk0[4][2], pk1[4][2];
        #pragma unroll
        for (int c = 0; c < 4; ++c)
            #pragma unroll
            for (int p = 0; p < 2; ++p) {
                pk0[c][p] = pack2(fexp2(s0[4 * c + 2 * p]),
                                  fexp2(s0[4 * c + 2 * p + 1]));
                pk1[c][p] = pack2(fexp2(s1[4 * c + 2 * p]),
                                  fexp2(s1[4 * c + 2 * p + 1]));
            }

        // O^T += V^T.P^T with sigma-permuted K axis: B-frag = own C quads
        #pragma unroll
        for (int ks = 0; ks < 4; ++ks) {
            const unsigned int (*src)[2] = (ks < 2) ? pk0 : pk1;
            const int c2 = (ks & 1) * 2;
            bf16x8 bp;
            unsigned int* bpu = (unsigned int*)&bp;
            bpu[0] = src[c2][0];     bpu[1] = src[c2][1];
            bpu[2] = src[c2 + 1][0]; bpu[3] = src[c2 + 1][1];
            bf16x8 va0 = *(const bf16x8*)&Vs[lq][ks * 16 + hf * 8];
            bf16x8 va1 = *(const bf16x8*)&Vs[32 + lq][ks * 16 + hf * 8];
            O[0] = __builtin_amdgcn_mfma_f32_32x32x16_bf16(va0, bp, O[0], 0, 0, 0);
            O[1] = __builtin_amdgcn_mfma_f32_32x32x16_bf16(va1, bp, O[1], 0, 0, 0);
            Ol   = __builtin_amdgcn_mfma_f32_32x32x16_bf16(onesA, bp, Ol, 0, 0, 0);
        }
    }

    // ---- combine the two kv-halves through LDS ----
    float* R    = (float*)&SM[0][0][0][0];    // [w4][64 d][32 q] fp32 = 32 KB
    float* Laux = R + 4 * 64 * 32;            // [w4][32 q] = 512 B

    __syncthreads();                          // everyone done with tiles
    if (sp == 1) {
        #pragma unroll
        for (int dt = 0; dt < 2; ++dt)
            #pragma unroll
            for (int r = 0; r < 16; ++r) {
                const int d = (r & 3) + 8 * (r >> 2) + 4 * hf + 32 * dt;
                R[(w4 * 64 + d) * 32 + lq] = O[dt][r];
            }
        if (hf == 0) Laux[w4 * 32 + lq] = Ol[0];
    }
    __syncthreads();
    if (sp == 0) {
        #pragma unroll
        for (int dt = 0; dt < 2; ++dt)
            #pragma unroll
            for (int r = 0; r < 16; ++r) {
                const int d = (r & 3) + 8 * (r >> 2) + 4 * hf + 32 * dt;
                O[dt][r] += R[(w4 * 64 + d) * 32 + lq];
            }
        const float lsum = Ol[0] + Laux[w4 * 32 + lq];
        const float linv = 1.0f / __shfl(lsum, lq);

        // direct store: lane owns row q = qs+lq; d quads at 32dt+8c+4hf
        unsigned short* ob = ctx + ((size_t)b * N_SEQ + qs + lq) * D_MODEL
                                 + h * DK + hf * 4;
        #pragma unroll
        for (int dt = 0; dt < 2; ++dt)
            #pragma unroll
            for (int c = 0; c < 4; ++c) {
                unsigned int w2[2];
                w2[0] = pack2(O[dt][4 * c + 0] * linv, O[dt][4 * c + 1] * linv);
                w2[1] = pack2(O[dt][4 * c + 2] * linv, O[dt][4 * c + 3] * linv);
                *(unsigned int*)(ob + dt * 32 + c * 8)     = w2[0];
                *(unsigned int*)(ob + dt * 32 + c * 8 + 2) = w2[1];
            }
    }
}

// ---------------------------------------------------------------------------
extern "C" void kernel_launch(void* const* d_in, const int* in_sizes, int n_in,
                              void* d_out, int out_size, void* d_ws, size_t ws_size,
                              hipStream_t stream)
{
    const float* x  = (const float*)d_in[0];
    const float* Wq = (const float*)d_in[1];
    const float* bq = (const float*)d_in[2];
    const float* Wk = (const float*)d_in[3];
    const float* bk = (const float*)d_in[4];
    const float* Wv = (const float*)d_in[5];
    const float* bv = (const float*)d_in[6];
    const float* Wo = (const float*)d_in[7];
    const float* bo = (const float*)d_in[8];
    float* out = (float*)d_out;

    const int M = in_sizes[0] / D_MODEL;        // 8192
    const int nb = M / N_SEQ;                   // 4
    const size_t NX = (size_t)M * D_MODEL;
    const size_t NW = (size_t)D_MODEL * D_MODEL;

    unsigned short* Wtq = (unsigned short*)d_ws;
    unsigned short* Wtk = Wtq + NW;
    unsigned short* Wtv = Wtk + NW;
    unsigned short* Wto = Wtv + NW;
    unsigned short* Qb  = Wto + NW;
    unsigned short* Kb  = Qb + NX;
    unsigned short* Vtb = Kb + NX;
    unsigned short* ctx = Vtb + NX;             // separate buffer (no aliasing)

    transpose_all<<<dim3(16, 16, 4), dim3(32, 8), 0, stream>>>(
        Wq, Wk, Wv, Wo, Wtq, Wtk, Wtv, Wto);

    gemm_qkv<<<dim3(D_MODEL / 128, M / 128, 3), 256, 0, stream>>>(
        x, Wtq, Wtk, Wtv, bq, bk, bv, Qb, Kb, Vtb);
    attn_mfma<<<dim3(NQT, H, nb), 512, 0, stream>>>(Qb, Kb, Vtb, ctx);
    gemm_o<<<dim3(D_MODEL / 128, M / 128), 256, 0, stream>>>(ctx, Wto, bo, out);
}

// Round 8
// 185.241 us; speedup vs baseline: 1.1735x; 1.0280x over previous
//
#include <hip/hip_runtime.h>
#include <math.h>

#define D_MODEL 512
#define N_SEQ   2048
#define H       8
#define DK      64
#define NQT     (N_SEQ / 128)   // q-tiles per (b,h) = 16

typedef __attribute__((ext_vector_type(8)))  short bf16x8;
typedef __attribute__((ext_vector_type(4)))  float f32x4;
typedef __attribute__((ext_vector_type(16))) float f32x16;

__device__ __forceinline__ unsigned short f2b(float f) {
    unsigned int u = __float_as_uint(f);
    u += 0x7FFF + ((u >> 16) & 1);          // round-to-nearest-even
    return (unsigned short)(u >> 16);
}

__device__ __forceinline__ unsigned int pack2(float lo, float hi) {
#if __has_builtin(__builtin_amdgcn_cvt_pk_bf16_f32)
    typedef __attribute__((ext_vector_type(2))) short bf16x2;
    bf16x2 p = __builtin_amdgcn_cvt_pk_bf16_f32(lo, hi);
    return (unsigned int)(unsigned short)p[0] |
           ((unsigned int)(unsigned short)p[1] << 16);
#else
    return (unsigned int)f2b(lo) | ((unsigned int)f2b(hi) << 16);
#endif
}

__device__ __forceinline__ float fexp2(float x) {
#if __has_builtin(__builtin_amdgcn_exp2f)
    return __builtin_amdgcn_exp2f(x);
#else
    return __expf(x * 0.6931471805599453f);
#endif
}

#define SC2 0.18033688011112042f    // (1/sqrt(64)) * log2(e), folded into Q

// ---------------------------------------------------------------------------
// All four W[512,512] fp32 -> Wt[n][k] bf16, one launch (z picks the matrix)
// ---------------------------------------------------------------------------
__global__ void transpose_all(
    const float* __restrict__ W0, const float* __restrict__ W1,
    const float* __restrict__ W2, const float* __restrict__ W3,
    unsigned short* __restrict__ T0, unsigned short* __restrict__ T1,
    unsigned short* __restrict__ T2, unsigned short* __restrict__ T3)
{
    const float* W; unsigned short* Wt;
    if      (blockIdx.z == 0) { W = W0; Wt = T0; }
    else if (blockIdx.z == 1) { W = W1; Wt = T1; }
    else if (blockIdx.z == 2) { W = W2; Wt = T2; }
    else                      { W = W3; Wt = T3; }

    __shared__ float t[32][33];
    const int tx = threadIdx.x, ty = threadIdx.y;
    const int x = blockIdx.x * 32 + tx;
    const int y0 = blockIdx.y * 32;
    for (int i = ty; i < 32; i += 8)
        t[i][tx] = W[(size_t)(y0 + i) * D_MODEL + x];
    __syncthreads();
    const int ox = blockIdx.y * 32 + tx;
    const int oy0 = blockIdx.x * 32;
    for (int i = ty; i < 32; i += 8)
        Wt[(size_t)(oy0 + i) * D_MODEL + ox] = f2b(t[tx][i]);
}

// ---------------------------------------------------------------------------
// bf16 MFMA GEMM body (16x16x32, 128x128 tile).  LDS is passed in by the
// caller so multiple template instantiations in one kernel SHARE the block
// (the r7 counters showed 73728 B = doubled LDS -> 2 blocks/CU).
// AMODE 1: A fp32, converted during staging.  AMODE 0: A bf16.
// SWAP 1 (Q/K): MFMA (Wfrag, xfrag) -> C rows = d, cols = tokens
//               -> packed ushort4 d-contiguous stores to [B,H,N,DK].
// SWAP 0: mode 1 V^T [B,H,DK,N] (token-packed), mode 2 fp32 [M,512].
// ---------------------------------------------------------------------------
template<int AMODE, int SWAP>
__device__ __forceinline__ void gemm_body(
    const void* __restrict__ Aptr,
    const unsigned short* __restrict__ Wt,
    const float* __restrict__ bias,
    void* __restrict__ out, int mode, int bx, int by, float sc,
    unsigned short (*As)[72], unsigned short (*Bs)[72])
{
    const int tid  = threadIdx.x;
    const int lane = tid & 63, wave = tid >> 6;
    const int m0 = by * 128, n0 = bx * 128;
    const int wm = (wave & 1) * 64, wn = (wave >> 1) * 64;
    const int cn = lane & 15, g = lane >> 4;

    const int srow = tid >> 1;
    const int scol = (tid & 1) * 32;
    const float* Agf = (const float*)Aptr + (size_t)(m0 + srow) * D_MODEL + scol;
    const unsigned short* Agb =
        (const unsigned short*)Aptr + (size_t)(m0 + srow) * D_MODEL + scol;
    const unsigned short* Bg = Wt + (size_t)(n0 + srow) * D_MODEL + scol;

    f32x4 acc[4][4];
    #pragma unroll
    for (int i = 0; i < 4; ++i)
        #pragma unroll
        for (int j = 0; j < 4; ++j)
            acc[i][j] = (f32x4){0.f, 0.f, 0.f, 0.f};

    for (int k0 = 0; k0 < D_MODEL; k0 += 64) {
        bf16x8 av[4], bv[4];
        #pragma unroll
        for (int q = 0; q < 4; ++q) {
            if (AMODE) {
                float4 f0 = *(const float4*)(Agf + k0 + q * 8);
                float4 f1 = *(const float4*)(Agf + k0 + q * 8 + 4);
                unsigned int* pv = (unsigned int*)&av[q];
                pv[0] = pack2(f0.x, f0.y); pv[1] = pack2(f0.z, f0.w);
                pv[2] = pack2(f1.x, f1.y); pv[3] = pack2(f1.z, f1.w);
            } else {
                av[q] = *(const bf16x8*)(Agb + k0 + q * 8);
            }
            bv[q] = *(const bf16x8*)(Bg + k0 + q * 8);
        }
        __syncthreads();
        #pragma unroll
        for (int q = 0; q < 4; ++q) {
            *(bf16x8*)&As[srow][scol + q * 8] = av[q];
            *(bf16x8*)&Bs[srow][scol + q * 8] = bv[q];
        }
        __syncthreads();

        #pragma unroll
        for (int ks = 0; ks < 2; ++ks) {
            bf16x8 af[4], bf[4];
            #pragma unroll
            for (int i = 0; i < 4; ++i)
                af[i] = *(const bf16x8*)&As[wm + i * 16 + cn][ks * 32 + g * 8];
            #pragma unroll
            for (int j = 0; j < 4; ++j)
                bf[j] = *(const bf16x8*)&Bs[wn + j * 16 + cn][ks * 32 + g * 8];
            #pragma unroll
            for (int i = 0; i < 4; ++i)
                #pragma unroll
                for (int j = 0; j < 4; ++j) {
                    if (SWAP)
                        acc[i][j] = __builtin_amdgcn_mfma_f32_16x16x32_bf16(
                            bf[j], af[i], acc[i][j], 0, 0, 0);
                    else
                        acc[i][j] = __builtin_amdgcn_mfma_f32_16x16x32_bf16(
                            af[i], bf[j], acc[i][j], 0, 0, 0);
                }
        }
    }

    if constexpr (SWAP) {
        unsigned short* o = (unsigned short*)out;
        #pragma unroll
        for (int j = 0; j < 4; ++j) {
            const int dbase = n0 + wn + j * 16 + g * 4;
            const int hh = dbase >> 6, dd = dbase & 63;
            float4 bb = *(const float4*)&bias[dbase];
            #pragma unroll
            for (int i = 0; i < 4; ++i) {
                const int tt = m0 + wm + i * 16 + cn;
                const int bi = tt >> 11, tok = tt & (N_SEQ - 1);
                ushort4 pk;
                pk.x = f2b((acc[i][j][0] + bb.x) * sc);
                pk.y = f2b((acc[i][j][1] + bb.y) * sc);
                pk.z = f2b((acc[i][j][2] + bb.z) * sc);
                pk.w = f2b((acc[i][j][3] + bb.w) * sc);
                *(ushort4*)(o + (((size_t)bi * H + hh) * N_SEQ + tok) * DK + dd) = pk;
            }
        }
    } else {                                 // mode 1: V^T [B,H,DK,N] bf16
        unsigned short* o = (unsigned short*)out;
        #pragma unroll
        for (int j = 0; j < 4; ++j) {
            const int n = n0 + wn + j * 16 + cn;
            const int h = n >> 6, d = n & 63;
            const float bb = bias[n];
            #pragma unroll
            for (int i = 0; i < 4; ++i) {
                const int m = m0 + wm + i * 16 + g * 4;
                const int b = m >> 11, t = m & (N_SEQ - 1);
                ushort4 pk;
                pk.x = f2b(acc[i][j][0] + bb);
                pk.y = f2b(acc[i][j][1] + bb);
                pk.z = f2b(acc[i][j][2] + bb);
                pk.w = f2b(acc[i][j][3] + bb);
                *(ushort4*)(o + (((size_t)b * H + h) * DK + d) * N_SEQ + t) = pk;
            }
        }
    }
    (void)mode;
}

__global__ __launch_bounds__(256, 4) void gemm_qkv(
    const float* __restrict__ x,
    const unsigned short* __restrict__ Wtq,
    const unsigned short* __restrict__ Wtk,
    const unsigned short* __restrict__ Wtv,
    const float* __restrict__ bq, const float* __restrict__ bk,
    const float* __restrict__ bv,
    unsigned short* __restrict__ Qb, unsigned short* __restrict__ Kb,
    unsigned short* __restrict__ Vtb)
{
    __shared__ unsigned short As[128][72];   // shared by all instantiations
    __shared__ unsigned short Bs[128][72];
    if (blockIdx.z == 0)
        gemm_body<1, 1>(x, Wtq, bq, Qb, 0, blockIdx.x, blockIdx.y, SC2, As, Bs);
    else if (blockIdx.z == 1)
        gemm_body<1, 1>(x, Wtk, bk, Kb, 0, blockIdx.x, blockIdx.y, 1.0f, As, Bs);
    else
        gemm_body<1, 0>(x, Wtv, bv, Vtb, 1, blockIdx.x, blockIdx.y, 1.0f, As, Bs);
}

// ---------------------------------------------------------------------------
// Output projection: 64x64 tile (1024 blocks -> 4 blocks/CU, vs 256 blocks
// = 1 block/CU for the 128-tile version).  A bf16 [M,512], out fp32 + bias.
// 4 waves, each a 32x32 quadrant (acc[2][2]).
// ---------------------------------------------------------------------------
__global__ __launch_bounds__(256, 4) void gemm_o(
    const unsigned short* __restrict__ A,
    const unsigned short* __restrict__ Wt,
    const float* __restrict__ bias, float* __restrict__ out)
{
    __shared__ unsigned short As[64][72];
    __shared__ unsigned short Bs[64][72];

    const int tid  = threadIdx.x;
    const int lane = tid & 63, wave = tid >> 6;
    const int m0 = blockIdx.y * 64, n0 = blockIdx.x * 64;
    const int wm = (wave & 1) * 32, wn = (wave >> 1) * 32;
    const int cn = lane & 15, g = lane >> 4;

    const int srow = tid >> 2;               // 0..63
    const int scol = (tid & 3) * 16;
    const unsigned short* Ag = A  + (size_t)(m0 + srow) * D_MODEL + scol;
    const unsigned short* Bg = Wt + (size_t)(n0 + srow) * D_MODEL + scol;

    f32x4 acc[2][2];
    #pragma unroll
    for (int i = 0; i < 2; ++i)
        #pragma unroll
        for (int j = 0; j < 2; ++j)
            acc[i][j] = (f32x4){0.f, 0.f, 0.f, 0.f};

    for (int k0 = 0; k0 < D_MODEL; k0 += 64) {
        bf16x8 av[2], bv[2];
        #pragma unroll
        for (int q = 0; q < 2; ++q) {
            av[q] = *(const bf16x8*)(Ag + k0 + q * 8);
            bv[q] = *(const bf16x8*)(Bg + k0 + q * 8);
        }
        __syncthreads();
        #pragma unroll
        for (int q = 0; q < 2; ++q) {
            *(bf16x8*)&As[srow][scol + q * 8] = av[q];
            *(bf16x8*)&Bs[srow][scol + q * 8] = bv[q];
        }
        __syncthreads();

        #pragma unroll
        for (int ks = 0; ks < 2; ++ks) {
            bf16x8 af[2], bf[2];
            #pragma unroll
            for (int i = 0; i < 2; ++i)
                af[i] = *(const bf16x8*)&As[wm + i * 16 + cn][ks * 32 + g * 8];
            #pragma unroll
            for (int j = 0; j < 2; ++j)
                bf[j] = *(const bf16x8*)&Bs[wn + j * 16 + cn][ks * 32 + g * 8];
            #pragma unroll
            for (int i = 0; i < 2; ++i)
                #pragma unroll
                for (int j = 0; j < 2; ++j)
                    acc[i][j] = __builtin_amdgcn_mfma_f32_16x16x32_bf16(
                        af[i], bf[j], acc[i][j], 0, 0, 0);
        }
    }

    #pragma unroll
    for (int j = 0; j < 2; ++j) {
        const int n = n0 + wn + j * 16 + cn;
        const float bb = bias[n];
        #pragma unroll
        for (int i = 0; i < 2; ++i)
            #pragma unroll
            for (int r = 0; r < 4; ++r) {
                const int m = m0 + wm + i * 16 + g * 4 + r;
                out[(size_t)m * D_MODEL + n] = acc[i][j][r] + bb;
            }
    }
}

// ---------------------------------------------------------------------------
// Flash attention, 32x32x16 MFMA, static softmax (Q pre-scaled by SC2).
// Zero-shuffle P path via K-axis permutation sigma = [q0,q2,q1,q3] per
// 16-kv chunk (V^T absorbs sigma at staging).  l via ones-A MFMA.
// Intra-block split-kv: 8 waves, waves 0-3 kv[0,1024), 4-7 kv[1024,2048);
// partials combine through LDS at the end.
// ---------------------------------------------------------------------------
__global__ __launch_bounds__(512, 4) void attn_mfma(
    const unsigned short* __restrict__ Q,
    const unsigned short* __restrict__ K,
    const unsigned short* __restrict__ Vt,
    unsigned short* __restrict__ ctx)
{
    __shared__ unsigned short SM[2][2][64][72];   // [kv-half][K|V][row][col]

    const int tid = threadIdx.x, lane = tid & 63, wave = tid >> 6;
    const int qt = blockIdx.x, h = blockIdx.y, b = blockIdx.z;
    const int sp = wave >> 2;                 // kv half
    const int w4 = wave & 3;                  // q-strip within tile
    const int lq = lane & 31, hf = lane >> 5;
    const int q0 = qt * 128;
    const int qs = q0 + w4 * 32;

    const size_t hb = (size_t)b * H + h;
    const unsigned short* Qp = Q  + hb * N_SEQ * DK;
    const unsigned short* Kp = K  + hb * N_SEQ * DK;
    const unsigned short* Vp = Vt + hb * DK * N_SEQ;

    bf16x8 qf[4];
    #pragma unroll
    for (int kd = 0; kd < 4; ++kd)
        qf[kd] = *(const bf16x8*)(Qp + (size_t)(qs + lq) * DK + kd * 16 + hf * 8);

    f32x16 O[2], Ol;
    #pragma unroll
    for (int r = 0; r < 16; ++r) { O[0][r] = 0.f; O[1][r] = 0.f; Ol[r] = 0.f; }

    bf16x8 onesA;                             // A ones-frag: row m==0 only
    {
        const short v = (lq == 0) ? (short)0x3F80 : (short)0;
        #pragma unroll
        for (int j = 0; j < 8; ++j) onesA[j] = v;
    }

    const int tl = tid & 255;                 // index within kv-half group
    const int krow = tl >> 2, kcol = (tl & 3) * 16;
    unsigned short (*Ks)[72] = SM[sp][0];
    unsigned short (*Vs)[72] = SM[sp][1];

    for (int it = 0; it < 16; ++it) {
        const int j0 = sp * (N_SEQ / 2) + it * 64;
        bf16x8 kv0 = *(const bf16x8*)(Kp + (size_t)(j0 + krow) * DK + kcol);
        bf16x8 kv1 = *(const bf16x8*)(Kp + (size_t)(j0 + krow) * DK + kcol + 8);
        bf16x8 vv0 = *(const bf16x8*)(Vp + (size_t)krow * N_SEQ + j0 + kcol);
        bf16x8 vv1 = *(const bf16x8*)(Vp + (size_t)krow * N_SEQ + j0 + kcol + 8);
        // sigma: swap middle quads of the 16-col chunk: store (q0,q2),(q1,q3)
        bf16x8 sw0, sw1;
        {
            ushort4* a = (ushort4*)&vv0;
            ushort4* c = (ushort4*)&vv1;
            ushort4* s0p = (ushort4*)&sw0;
            ushort4* s1p = (ushort4*)&sw1;
            s0p[0] = a[0]; s0p[1] = c[0];
            s1p[0] = a[1]; s1p[1] = c[1];
        }
        __syncthreads();
        *(bf16x8*)&Ks[krow][kcol]     = kv0;
        *(bf16x8*)&Ks[krow][kcol + 8] = kv1;
        *(bf16x8*)&Vs[krow][kcol]     = sw0;
        *(bf16x8*)&Vs[krow][kcol + 8] = sw1;
        __syncthreads();

        // S^T[kv][q] (log2 domain): lane holds col q=lq, rows kv per C map
        f32x16 s0, s1;
        #pragma unroll
        for (int r = 0; r < 16; ++r) { s0[r] = 0.f; s1[r] = 0.f; }
        #pragma unroll
        for (int kd = 0; kd < 4; ++kd) {
            bf16x8 a0 = *(const bf16x8*)&Ks[lq][kd * 16 + hf * 8];
            bf16x8 a1 = *(const bf16x8*)&Ks[32 + lq][kd * 16 + hf * 8];
            s0 = __builtin_amdgcn_mfma_f32_32x32x16_bf16(a0, qf[kd], s0, 0, 0, 0);
            s1 = __builtin_amdgcn_mfma_f32_32x32x16_bf16(a1, qf[kd], s1, 0, 0, 0);
        }

        // p = exp2(s); pk[c][p] = packed regs (4c+2p, 4c+2p+1) = kv quads
        unsigned int pk0[4][2], pk1[4][2];
        #pragma unroll
        for (int c = 0; c < 4; ++c)
            #pragma unroll
            for (int p = 0; p < 2; ++p) {
                pk0[c][p] = pack2(fexp2(s0[4 * c + 2 * p]),
                                  fexp2(s0[4 * c + 2 * p + 1]));
                pk1[c][p] = pack2(fexp2(s1[4 * c + 2 * p]),
                                  fexp2(s1[4 * c + 2 * p + 1]));
            }

        // O^T += V^T.P^T with sigma-permuted K axis: B-frag = own C quads
        #pragma unroll
        for (int ks = 0; ks < 4; ++ks) {
            const unsigned int (*src)[2] = (ks < 2) ? pk0 : pk1;
            const int c2 = (ks & 1) * 2;
            bf16x8 bp;
            unsigned int* bpu = (unsigned int*)&bp;
            bpu[0] = src[c2][0];     bpu[1] = src[c2][1];
            bpu[2] = src[c2 + 1][0]; bpu[3] = src[c2 + 1][1];
            bf16x8 va0 = *(const bf16x8*)&Vs[lq][ks * 16 + hf * 8];
            bf16x8 va1 = *(const bf16x8*)&Vs[32 + lq][ks * 16 + hf * 8];
            O[0] = __builtin_amdgcn_mfma_f32_32x32x16_bf16(va0, bp, O[0], 0, 0, 0);
            O[1] = __builtin_amdgcn_mfma_f32_32x32x16_bf16(va1, bp, O[1], 0, 0, 0);
            Ol   = __builtin_amdgcn_mfma_f32_32x32x16_bf16(onesA, bp, Ol, 0, 0, 0);
        }
    }

    // ---- combine the two kv-halves through LDS ----
    float* R    = (float*)&SM[0][0][0][0];    // [w4][64 d][32 q] fp32 = 32 KB
    float* Laux = R + 4 * 64 * 32;            // [w4][32 q] = 512 B

    __syncthreads();                          // everyone done with tiles
    if (sp == 1) {
        #pragma unroll
        for (int dt = 0; dt < 2; ++dt)
            #pragma unroll
            for (int r = 0; r < 16; ++r) {
                const int d = (r & 3) + 8 * (r >> 2) + 4 * hf + 32 * dt;
                R[(w4 * 64 + d) * 32 + lq] = O[dt][r];
            }
        if (hf == 0) Laux[w4 * 32 + lq] = Ol[0];
    }
    __syncthreads();
    if (sp == 0) {
        #pragma unroll
        for (int dt = 0; dt < 2; ++dt)
            #pragma unroll
            for (int r = 0; r < 16; ++r) {
                const int d = (r & 3) + 8 * (r >> 2) + 4 * hf + 32 * dt;
                O[dt][r] += R[(w4 * 64 + d) * 32 + lq];
            }
        const float lsum = Ol[0] + Laux[w4 * 32 + lq];
        const float linv = 1.0f / __shfl(lsum, lq);

        // direct store: lane owns row q = qs+lq; d quads at 32dt+8c+4hf
        unsigned short* ob = ctx + ((size_t)b * N_SEQ + qs + lq) * D_MODEL
                                 + h * DK + hf * 4;
        #pragma unroll
        for (int dt = 0; dt < 2; ++dt)
            #pragma unroll
            for (int c = 0; c < 4; ++c) {
                unsigned int w2[2];
                w2[0] = pack2(O[dt][4 * c + 0] * linv, O[dt][4 * c + 1] * linv);
                w2[1] = pack2(O[dt][4 * c + 2] * linv, O[dt][4 * c + 3] * linv);
                *(unsigned int*)(ob + dt * 32 + c * 8)     = w2[0];
                *(unsigned int*)(ob + dt * 32 + c * 8 + 2) = w2[1];
            }
    }
}

// ---------------------------------------------------------------------------
extern "C" void kernel_launch(void* const* d_in, const int* in_sizes, int n_in,
                              void* d_out, int out_size, void* d_ws, size_t ws_size,
                              hipStream_t stream)
{
    const float* x  = (const float*)d_in[0];
    const float* Wq = (const float*)d_in[1];
    const float* bq = (const float*)d_in[2];
    const float* Wk = (const float*)d_in[3];
    const float* bk = (const float*)d_in[4];
    const float* Wv = (const float*)d_in[5];
    const float* bv = (const float*)d_in[6];
    const float* Wo = (const float*)d_in[7];
    const float* bo = (const float*)d_in[8];
    float* out = (float*)d_out;

    const int M = in_sizes[0] / D_MODEL;        // 8192
    const int nb = M / N_SEQ;                   // 4
    const size_t NX = (size_t)M * D_MODEL;
    const size_t NW = (size_t)D_MODEL * D_MODEL;

    unsigned short* Wtq = (unsigned short*)d_ws;
    unsigned short* Wtk = Wtq + NW;
    unsigned short* Wtv = Wtk + NW;
    unsigned short* Wto = Wtv + NW;
    unsigned short* Qb  = Wto + NW;
    unsigned short* Kb  = Qb + NX;
    unsigned short* Vtb = Kb + NX;
    unsigned short* ctx = Vtb + NX;

    transpose_all<<<dim3(16, 16, 4), dim3(32, 8), 0, stream>>>(
        Wq, Wk, Wv, Wo, Wtq, Wtk, Wtv, Wto);

    gemm_qkv<<<dim3(D_MODEL / 128, M / 128, 3), 256, 0, stream>>>(
        x, Wtq, Wtk, Wtv, bq, bk, bv, Qb, Kb, Vtb);
    attn_mfma<<<dim3(NQT, H, nb), 512, 0, stream>>>(Qb, Kb, Vtb, ctx);
    gemm_o<<<dim3(D_MODEL / 64, M / 64), 256, 0, stream>>>(ctx, Wto, bo, out);
}